// Round 1
// baseline (798.649 us; speedup 1.0000x reference)
//
#include <hip/hip_runtime.h>

#define EMB_DIM 128
#define NEG 5
#define TPB 256
#define GRID_BLOCKS 2048   // ~8 blocks/CU worth of waves; grid-stride covers B

// One half-wave (32 lanes) per batch element. Each lane loads a float4
// (16 B) of the 128-float row -> one coalesced 512 B transaction per row.
// 4 waves/block * 2 elems/wave = 8 elements per 256-thread block per
// grid-stride iteration. Partial sums go to a workspace array (plain
// stores) instead of a same-address device atomic: 8192 serialized
// cross-XCD atomics were ~800us of the previous 827us.
__global__ __launch_bounds__(TPB) void skipgram_loss_kernel(
    const float* __restrict__ u_weight,
    const float* __restrict__ v_weight,
    const int*   __restrict__ pos_u,
    const int*   __restrict__ pos_v,
    const int*   __restrict__ neg_v,
    float* __restrict__ partials,
    int B)
{
    const int lane        = threadIdx.x & 63;
    const int sub         = lane & 31;        // lane within half-wave
    const int half        = lane >> 5;        // which half-wave
    const int waveInBlock = threadIdx.x >> 6; // 0..3
    const int hw          = waveInBlock * 2 + half; // half-wave id 0..7

    float loss = 0.0f;

    for (int b = blockIdx.x * 8 + hw; b < B; b += gridDim.x * 8) {
        const int pu = pos_u[b];
        const int pv = pos_v[b];

        int nidx[NEG];
        #pragma unroll
        for (int k = 0; k < NEG; ++k) nidx[k] = neg_v[b * NEG + k];

        const float4 u4 = ((const float4*)(u_weight + (size_t)pu * EMB_DIM))[sub];
        const float4 v4 = ((const float4*)(v_weight + (size_t)pv * EMB_DIM))[sub];
        float4 n4[NEG];
        #pragma unroll
        for (int k = 0; k < NEG; ++k)
            n4[k] = ((const float4*)(v_weight + (size_t)nidx[k] * EMB_DIM))[sub];

        // positive score
        float dot = u4.x * v4.x + u4.y * v4.y + u4.z * v4.z + u4.w * v4.w;
        #pragma unroll
        for (int m = 16; m >= 1; m >>= 1)
            dot += __shfl_xor(dot, m, 64);
        float score = fminf(fmaxf(dot, -10.0f), 10.0f);
        loss += log1pf(__expf(-score));  // -log_sigmoid(score)

        // negative scores
        #pragma unroll
        for (int k = 0; k < NEG; ++k) {
            float nd = u4.x * n4[k].x + u4.y * n4[k].y + u4.z * n4[k].z + u4.w * n4[k].w;
            #pragma unroll
            for (int m = 16; m >= 1; m >>= 1)
                nd += __shfl_xor(nd, m, 64);
            float ns = fminf(fmaxf(nd, -10.0f), 10.0f);
            loss += log1pf(__expf(ns)); // -log_sigmoid(-ns)
        }
    }

    // Block reduce: after the xor-butterfly every lane of a half-wave holds
    // the same reduced value, so one lane per half-wave contributes.
    __shared__ float hsum[8];
    if (sub == 0) hsum[hw] = loss;
    __syncthreads();
    if (threadIdx.x == 0) {
        float s = 0.0f;
        #pragma unroll
        for (int i = 0; i < 8; ++i) s += hsum[i];
        partials[blockIdx.x] = s;   // plain store, no atomic
    }
}

// Single-block reduction of the per-block partials; writes out directly
// (overwrites the 0xAA poison, so no memset needed).
__global__ __launch_bounds__(1024) void reduce_partials_kernel(
    const float* __restrict__ partials, float* __restrict__ out,
    int n, float inv_b)
{
    float s = 0.0f;
    for (int i = threadIdx.x; i < n; i += 1024) s += partials[i];

    #pragma unroll
    for (int m = 32; m >= 1; m >>= 1)
        s += __shfl_xor(s, m, 64);

    __shared__ float wsum[16];
    const int w = threadIdx.x >> 6;
    if ((threadIdx.x & 63) == 0) wsum[w] = s;
    __syncthreads();
    if (threadIdx.x == 0) {
        float t = 0.0f;
        #pragma unroll
        for (int i = 0; i < 16; ++i) t += wsum[i];
        out[0] = t * inv_b;
    }
}

extern "C" void kernel_launch(void* const* d_in, const int* in_sizes, int n_in,
                              void* d_out, int out_size, void* d_ws, size_t ws_size,
                              hipStream_t stream) {
    const float* u_weight = (const float*)d_in[0];
    const float* v_weight = (const float*)d_in[1];
    const int*   pos_u    = (const int*)d_in[2];
    const int*   pos_v    = (const int*)d_in[3];
    const int*   neg_v    = (const int*)d_in[4];
    float* out      = (float*)d_out;
    float* partials = (float*)d_ws;   // GRID_BLOCKS floats = 8 KB

    const int B = in_sizes[2];

    skipgram_loss_kernel<<<GRID_BLOCKS, TPB, 0, stream>>>(
        u_weight, v_weight, pos_u, pos_v, neg_v, partials, B);

    reduce_partials_kernel<<<1, 1024, 0, stream>>>(
        partials, out, GRID_BLOCKS, 1.0f / (float)B);
}